// Round 4
// baseline (62.677 us; speedup 1.0000x reference)
//
#include <hip/hip_runtime.h>
#include <math.h>

#define BB 16
#define KK 5
#define NN 4096
#define DD 1024
#define TOPK 9
#define EPSV 1e-12f
#define RPB 64   // patch rows per block in sims kernel

typedef float f32x4 __attribute__((ext_vector_type(4)));

// ---------------- kernel A: fused cue-norm + sims + patch inv-norms -------
// grid = (N/RPB, B), 256 threads = 4 waves. float2-packed accumulators so
// the backend can emit v_pk_fma_f32 (2-wide f32 FMA) -> half the VALU issue
// per byte streamed.
__global__ __launch_bounds__(256) void sims_kernel(
    const float* __restrict__ patches, const float* __restrict__ cue,
    float* __restrict__ sims, float* __restrict__ invn) {
  int b = blockIdx.y;
  int row0 = blockIdx.x * RPB;
  int wid = threadIdx.x >> 6;
  int lane = threadIdx.x & 63;

  // this lane's cue fragments: 5 cues x 8 float2 = 80 VGPRs
  float2 c[KK][8];
  const float4* cb = (const float4*)(cue + (size_t)b * KK * DD);
#pragma unroll
  for (int k = 0; k < KK; ++k)
#pragma unroll
    for (int j = 0; j < 4; ++j) {
      float4 v = cb[k * 256 + j * 64 + lane];
      c[k][2 * j].x = v.x; c[k][2 * j].y = v.y;
      c[k][2 * j + 1].x = v.z; c[k][2 * j + 1].y = v.w;
    }

  // normalize cues fully in-register (each wave redundantly; no syncs)
#pragma unroll
  for (int k = 0; k < KK; ++k) {
    float2 s2; s2.x = 0.f; s2.y = 0.f;
#pragma unroll
    for (int j = 0; j < 8; ++j) {
      s2.x = fmaf(c[k][j].x, c[k][j].x, s2.x);
      s2.y = fmaf(c[k][j].y, c[k][j].y, s2.y);
    }
    float s = s2.x + s2.y;
#pragma unroll
    for (int off = 32; off; off >>= 1) s += __shfl_xor(s, off, 64);
    float inv = 1.0f / fmaxf(sqrtf(s), EPSV);
#pragma unroll
    for (int j = 0; j < 8; ++j) { c[k][j].x *= inv; c[k][j].y *= inv; }
  }

  const f32x4* pb = (const f32x4*)(patches + (size_t)b * NN * DD);

#pragma unroll 2
  for (int r = wid; r < RPB; r += 4) {
    int row = row0 + r;
    const f32x4* p4 = pb + (size_t)row * 256;
    float2 a[KK], n2;
#pragma unroll
    for (int k = 0; k < KK; ++k) { a[k].x = 0.f; a[k].y = 0.f; }
    n2.x = 0.f; n2.y = 0.f;
#pragma unroll
    for (int j = 0; j < 4; ++j) {
      f32x4 p = __builtin_nontemporal_load(&p4[j * 64 + lane]);
      float2 plo; plo.x = p.x; plo.y = p.y;
      float2 phi; phi.x = p.z; phi.y = p.w;
      n2.x = fmaf(plo.x, plo.x, n2.x);
      n2.y = fmaf(plo.y, plo.y, n2.y);
      n2.x = fmaf(phi.x, phi.x, n2.x);
      n2.y = fmaf(phi.y, phi.y, n2.y);
#pragma unroll
      for (int k = 0; k < KK; ++k) {
        a[k].x = fmaf(plo.x, c[k][2 * j].x, a[k].x);
        a[k].y = fmaf(plo.y, c[k][2 * j].y, a[k].y);
        a[k].x = fmaf(phi.x, c[k][2 * j + 1].x, a[k].x);
        a[k].y = fmaf(phi.y, c[k][2 * j + 1].y, a[k].y);
      }
    }
    float acc0 = a[0].x + a[0].y;
    float acc1 = a[1].x + a[1].y;
    float acc2 = a[2].x + a[2].y;
    float acc3 = a[3].x + a[3].y;
    float acc4 = a[4].x + a[4].y;
    float nr = n2.x + n2.y;
#pragma unroll
    for (int off = 32; off; off >>= 1) {
      nr   += __shfl_xor(nr,   off, 64);
      acc0 += __shfl_xor(acc0, off, 64);
      acc1 += __shfl_xor(acc1, off, 64);
      acc2 += __shfl_xor(acc2, off, 64);
      acc3 += __shfl_xor(acc3, off, 64);
      acc4 += __shfl_xor(acc4, off, 64);
    }
    if (lane == 0) {
      float inv = 1.0f / fmaxf(sqrtf(nr), EPSV);
      invn[b * NN + row] = inv;
      sims[((size_t)b * KK + 0) * NN + row] = acc0 * inv;
      sims[((size_t)b * KK + 1) * NN + row] = acc1 * inv;
      sims[((size_t)b * KK + 2) * NN + row] = acc2 * inv;
      sims[((size_t)b * KK + 3) * NN + row] = acc3 * inv;
      sims[((size_t)b * KK + 4) * NN + row] = acc4 * inv;
    }
  }
}

// ---------------- kernel B: register top-9 + gather-mean ----------------
// grid = B*K blocks, 256 threads = 4 waves. Each wave holds 1024 sims in
// 16 packed u64 keys/thread; 9 iterations of {local max, 6-step butterfly,
// invalidate} with NO syncthreads; then a 36->9 merge in wave 0; then the
// gather with all 9 row-loads in flight.
__global__ __launch_bounds__(256) void topk_gather_kernel(
    const float* __restrict__ patches, const float* __restrict__ sims,
    const float* __restrict__ invn, float* __restrict__ out) {
  int bk = blockIdx.x;  // 0..B*K
  int b = bk / KK;
  int wid = threadIdx.x >> 6, lane = threadIdx.x & 63;

  // load the sims row into packed keys: (mapped_f32 << 32) | ~idx
  unsigned long long key[16];
  const float4* srow = (const float4*)(sims + (size_t)bk * NN);
#pragma unroll
  for (int j = 0; j < 4; ++j) {
    float4 v = srow[j * 256 + threadIdx.x];
    int base = 4 * (j * 256 + threadIdx.x);
    float vv[4] = {v.x, v.y, v.z, v.w};
#pragma unroll
    for (int e = 0; e < 4; ++e) {
      unsigned u = __float_as_uint(vv[e]);
      u = (u & 0x80000000u) ? ~u : (u | 0x80000000u);
      key[j * 4 + e] =
          ((unsigned long long)u << 32) | (unsigned)(~(base + e));
    }
  }

  // per-wave top-9 (register-only, no block syncs)
  unsigned long long win[TOPK];
#pragma unroll
  for (int it = 0; it < TOPK; ++it) {
    unsigned long long m = key[0];
#pragma unroll
    for (int j = 1; j < 16; ++j) m = key[j] > m ? key[j] : m;
#pragma unroll
    for (int off = 32; off; off >>= 1) {
      unsigned long long o = __shfl_xor(m, off, 64);
      m = o > m ? o : m;
    }
    win[it] = m;
#pragma unroll
    for (int j = 0; j < 16; ++j)
      if (key[j] == m) key[j] = 0ull;
  }

  __shared__ unsigned long long cand[4 * TOPK];
  __shared__ int sel_idx[TOPK];
  __shared__ float sel_inv[TOPK];
  if (lane == 0) {
#pragma unroll
    for (int it = 0; it < TOPK; ++it) cand[wid * TOPK + it] = win[it];
  }
  __syncthreads();

  // wave 0 merges the 36 candidates -> global top-9
  if (wid == 0) {
    unsigned long long k2 = (lane < 4 * TOPK) ? cand[lane] : 0ull;
    unsigned long long mm[TOPK];
#pragma unroll
    for (int it = 0; it < TOPK; ++it) {
      unsigned long long m = k2;
#pragma unroll
      for (int off = 32; off; off >>= 1) {
        unsigned long long o = __shfl_xor(m, off, 64);
        m = o > m ? o : m;
      }
      mm[it] = m;
      if (k2 == m) k2 = 0ull;
    }
    if (lane == 0) {
#pragma unroll
      for (int it = 0; it < TOPK; ++it) {
        int idx = (int)(~(unsigned)(mm[it] & 0xFFFFFFFFu));
        sel_idx[it] = idx;
        sel_inv[it] = invn[b * NN + idx];  // 9 independent loads in flight
      }
    }
  }
  __syncthreads();

  // gather: each thread accumulates one float4 column chunk across 9 rows
  const float4* pb = (const float4*)(patches + (size_t)b * NN * DD);
  float4 acc; acc.x = acc.y = acc.z = acc.w = 0.f;
#pragma unroll
  for (int it = 0; it < TOPK; ++it) {
    float inv = sel_inv[it];
    float4 p = pb[(size_t)sel_idx[it] * 256 + threadIdx.x];
    acc.x += p.x * inv; acc.y += p.y * inv;
    acc.z += p.z * inv; acc.w += p.w * inv;
  }
  const float inv9 = 1.0f / 9.0f;
  float4 o;
  o.x = acc.x * inv9; o.y = acc.y * inv9;
  o.z = acc.z * inv9; o.w = acc.w * inv9;
  ((float4*)(out + (size_t)bk * DD))[threadIdx.x] = o;
}

extern "C" void kernel_launch(void* const* d_in, const int* in_sizes, int n_in,
                              void* d_out, int out_size, void* d_ws, size_t ws_size,
                              hipStream_t stream) {
  const float* cue = (const float*)d_in[0];      // (B, K, D) f32
  const float* patches = (const float*)d_in[1];  // (B, N, D) f32
  float* out = (float*)d_out;                    // (B, K, D) f32

  // workspace layout (floats)
  float* invn = (float*)d_ws;                    // B*N   = 65536
  float* sims = invn + (size_t)BB * NN;          // B*K*N = 327680

  dim3 g2(NN / RPB, BB);
  sims_kernel<<<g2, 256, 0, stream>>>(patches, cue, sims, invn);
  topk_gather_kernel<<<BB * KK, 256, 0, stream>>>(patches, sims, invn, out);
}